// Round 23
// baseline (402.724 us; speedup 1.0000x reference)
//
#include <hip/hip_runtime.h>
#include <hip/hip_fp16.h>

#define DEVINL __device__ __forceinline__

typedef _Float16 v4h __attribute__((ext_vector_type(4)));
typedef float    v4f __attribute__((ext_vector_type(4)));

constexpr int NUSER = 50000;
constexpr int NITEM = 50000;
constexpr int NTOT  = 100000;   // NUM_USER + NUM_ITEM
constexpr int DF    = 128;
constexpr int D     = 64;
constexpr int NE    = 2000000;
constexpr int TR    = 32;       // tile rows (100000/32 = 3125 tiles)
constexpr int ROWH  = 72;       // padded LDS row stride (halves)
constexpr int NCHUNK = 4;                             // src chunks (3.2MB < 4MB L2)
constexpr int CSPAN  = NTOT / NCHUNK;                 // 25000
constexpr int CCAP   = 32;      // per-chunk cap: 32 u16 = one 64B line
constexpr int CAP    = NCHUNK * CCAP;                 // 128 u16 slots/node
constexpr int NW     = 512;     // node windows
constexpr int NPW    = 196;     // nodes per window
constexpr int WCAP   = 4608;    // per-window stream cap
constexpr int PBLK   = 1024;                          // partition blocks
constexpr int EPB    = (NE + PBLK - 1) / PBLK;        // 1954 edges/block
constexpr int EPT    = (EPB + 255) / 256;             // 8 entries/thread

DEVINL float leaky(float v) { return v > 0.f ? v : 0.01f * v; }

DEVINL float2 h2f2(unsigned u) {
  __half2 h = *reinterpret_cast<__half2*>(&u);
  return __half22float2(h);
}

// ---------------------------------------------------------------------------
// User half of init: x16[r] = normalize(pref[r]). One wave per row.
// Block 0 also zeroes wcur (saves a separate k_zero dispatch).
__global__ __launch_bounds__(256) void k_init_user(
    const float* __restrict__ pref, __half* __restrict__ x16,
    int* __restrict__ wcur) {
  if (blockIdx.x == 0) {
    for (int i = threadIdx.x; i < NW + 64; i += 256) wcur[i] = 0;
  }
  int wid  = (blockIdx.x * blockDim.x + threadIdx.x) >> 6;
  int lane = threadIdx.x & 63;
  if (wid >= NUSER) return;
  float v = pref[(size_t)wid * D + lane];
  float ss = v * v;
#pragma unroll
  for (int o = 32; o; o >>= 1) ss += __shfl_xor(ss, o);
  float inv = 1.0f / fmaxf(sqrtf(ss), 1e-12f);
  x16[(size_t)wid * D + lane] = __float2half(v * inv);
}

// Item half: x16[NUSER+r] = normalize(feat[r] @ mlp_w.T + mlp_b).
__global__ __launch_bounds__(512) void k_init_item(
    const float* __restrict__ feat, const float* __restrict__ mlp_w,
    const float* __restrict__ mlp_b, __half* __restrict__ x16) {
  __shared__ float sF[TR * DF];        // 16 KB feature tile
  __shared__ float sP[2][TR][D];       // 16 KB partial sums (per k-half)
  int tid  = threadIdx.x;
  int lane = tid & 63;
  int wv   = tid >> 6;     // 0..7
  int kh   = wv & 1;       // k-half
  int rg   = wv >> 1;      // row group 0..3
  float wh[D];
  const float4* wp = (const float4*)(mlp_w + (size_t)lane * DF + kh * D);
#pragma unroll
  for (int k = 0; k < D / 4; ++k) {
    float4 t = wp[k];
    wh[4 * k] = t.x; wh[4 * k + 1] = t.y; wh[4 * k + 2] = t.z; wh[4 * k + 3] = t.w;
  }
  float bias = mlp_b[lane];
  int t = blockIdx.x;
  {
    const float4* base = (const float4*)(feat + (size_t)t * TR * DF);
    float4* dstl = (float4*)sF;
#pragma unroll
    for (int s = 0; s < 2; ++s) {
      int slot = tid + s * 512;
      int gr = t * TR + (slot >> 5);
      float4 v = make_float4(0.f, 0.f, 0.f, 0.f);
      if (gr < NITEM) v = base[slot];
      dstl[slot] = v;
    }
  }
  __syncthreads();
#pragma unroll
  for (int rr = 0; rr < 8; ++rr) {
    int r = rg * 8 + rr;
    const float4* fr = (const float4*)&sF[r * DF + kh * D];
    float acc = 0.f;
#pragma unroll
    for (int k = 0; k < D / 4; ++k) {
      float4 a = fr[k];   // uniform LDS read -> broadcast
      acc += a.x * wh[4 * k] + a.y * wh[4 * k + 1] + a.z * wh[4 * k + 2] + a.w * wh[4 * k + 3];
    }
    sP[kh][r][lane] = acc;
  }
  __syncthreads();
#pragma unroll
  for (int rr = 0; rr < 4; ++rr) {
    int r = wv * 4 + rr;
    int gr = t * TR + r;
    float v = sP[0][r][lane] + sP[1][r][lane] + bias;
    float ss = v * v;
#pragma unroll
    for (int o = 32; o; o >>= 1) ss += __shfl_xor(ss, o);
    float inv = 1.0f / fmaxf(sqrtf(ss), 1e-12f);
    if (gr < NITEM) x16[(size_t)(NUSER + gr) * D + lane] = __float2half(v * inv);
  }
}

// ---------------------------------------------------------------------------
// Phase 1: single-pass 512-way partition, register-cached edges,
// WAVE-LEVEL shfl scan (2 barriers instead of 18).
__global__ __launch_bounds__(256) void k_part(
    const int* __restrict__ src, const int* __restrict__ dst,
    int* __restrict__ wcur, unsigned* __restrict__ part) {
  __shared__ int hcnt[NW];      // 2 KB
  __shared__ int sc[NW];        // 2 KB (inclusive scan)
  __shared__ int gbase[NW];     // 2 KB
  __shared__ int hcur[NW];      // 2 KB
  __shared__ int wtot[4];
  __shared__ unsigned buf[EPB]; // 7.8 KB
  int tid = threadIdx.x;
  int wvv = tid >> 6, lane = tid & 63;
  int e0 = blockIdx.x * EPB, e1 = min(NE, e0 + EPB);
  for (int i = tid; i < NW; i += 256) { hcnt[i] = 0; hcur[i] = 0; }
  __syncthreads();
  unsigned ent[EPT];
  int wid[EPT];
#pragma unroll
  for (int i = 0; i < EPT; ++i) {
    int e = e0 + tid + i * 256;
    int w = -1; unsigned v = 0;
    if (e < e1) {
      int d = dst[e];
      int s = src[e];
      w = d / NPW;
      v = ((unsigned)(d - w * NPW) << 17) | (unsigned)s;
      atomicAdd(&hcnt[w], 1);
    }
    ent[i] = v; wid[i] = w;
  }
  __syncthreads();
  // wave-level inclusive scan: wave v owns bins [128v, 128v+128), 2 per lane
  int b0 = 128 * wvv + 2 * lane;
  int s0 = hcnt[b0], s1 = hcnt[b0 + 1];
  int pair = s0 + s1;
#pragma unroll
  for (int o = 1; o < 64; o <<= 1) {
    int t = __shfl_up(pair, o);      // convergent
    if (lane >= o) pair += t;
  }
  if (lane == 63) wtot[wvv] = pair;  // wave total
  __syncthreads();
  int prefix = 0;
#pragma unroll
  for (int v = 0; v < 4; ++v) prefix += (v < wvv) ? wtot[v] : 0;
  sc[b0]     = prefix + pair - s1;   // inclusive up to b0
  sc[b0 + 1] = prefix + pair;        // inclusive up to b0+1
  // global reservation (512 concurrent atomics, distinct addresses)
  for (int i = tid; i < NW; i += 256)
    gbase[i] = atomicAdd(&wcur[i], hcnt[i]);
  __syncthreads();
  // scatter from registers into LDS-bucketed runs
#pragma unroll
  for (int i = 0; i < EPT; ++i) {
    int w = wid[i];
    if (w >= 0) {
      int idx = atomicAdd(&hcur[w], 1);
      buf[sc[w] - hcnt[w] + idx] = ent[i];
    }
  }
  __syncthreads();
  // write-out: wave v handles bins v, v+4, ... (each bin ~4 entries)
  for (int b = wvv; b < NW; b += 4) {
    int len = hcnt[b];
    int lb = sc[b] - len;
    int gb = gbase[b];
    unsigned* out = part + (size_t)b * WCAP;
    for (int i = lane; i < len; i += 64)
      if (gb + i < WCAP) out[gb + i] = buf[lb + i];
  }
}

// ---------------------------------------------------------------------------
// Phase 2: LDS-bucketed scatter (reads only its own stream, coalesced out).
__global__ __launch_bounds__(256) void k_scatter_lds(
    const unsigned* __restrict__ part, const int* __restrict__ wcur,
    int* __restrict__ cursor, unsigned short* __restrict__ csr) {
  __shared__ unsigned short lbuck[NPW * CAP];
  __shared__ int lcur[NPW * NCHUNK];
  int tid = threadIdx.x;
  int w   = blockIdx.x;
  int nlo = w * NPW;
  int nn  = min(NPW, NTOT - nlo);
  if (nn <= 0) return;
  for (int i = tid; i < NPW * NCHUNK; i += 256) lcur[i] = 0;
  __syncthreads();
  int cnt = min(wcur[w], WCAP);
  const unsigned* basep = part + (size_t)w * WCAP;
  for (int e = tid; e < cnt; e += 256) {
    unsigned v = basep[e];
    int dl = (int)(v >> 17);
    int s  = (int)(v & 0x1ffffu);
    int c  = s / CSPAN;
    int p  = atomicAdd(&lcur[dl * NCHUNK + c], 1);
    if (p < CCAP) lbuck[dl * CAP + c * CCAP + p] = (unsigned short)(s - c * CSPAN);
  }
  __syncthreads();
  unsigned* gcsr = (unsigned*)(csr + (size_t)nlo * CAP);
  const unsigned* lsrc = (const unsigned*)lbuck;
  int words = nn * (CAP / 2);
  for (int i = tid; i < words; i += 256) gcsr[i] = lsrc[i];
  int* gcur = cursor + (size_t)nlo * NCHUNK;
  for (int i = tid; i < nn * NCHUNK; i += 256) gcur[i] = lcur[i];
}

// ---------------------------------------------------------------------------
// agg16[n] = fp16( sum over bucket of x16[src] ), f32 accum. CONVERGENT shfl.
__global__ __launch_bounds__(256) void k_agg(
    const __half* __restrict__ x16, const int* __restrict__ cnt,
    const unsigned short* __restrict__ csr, __half* __restrict__ agg16) {
  int wid  = (blockIdx.x * blockDim.x + threadIdx.x) >> 6;
  int lane = threadIdx.x & 63;
  if (wid >= NTOT) return;
  int g = lane >> 3;
  int q = lane & 7;
  int4 c4 = *(const int4*)(cnt + ((size_t)wid << 2));
  unsigned w = ((const unsigned*)(csr + (size_t)wid * CAP))[lane];
  float a[8] = {0.f, 0.f, 0.f, 0.f, 0.f, 0.f, 0.f, 0.f};
#pragma unroll
  for (int c = 0; c < NCHUNK; ++c) {
    int deg = min(c == 0 ? c4.x : c == 1 ? c4.y : c == 2 ? c4.z : c4.w, CCAP);
    int base = c * CSPAN;
    int e = 0;
    for (; e + 8 <= deg; e += 8) {
      unsigned u = __shfl(w, c * 16 + ((e + g) >> 1));
      int s = base + (int)((u >> (((e + g) & 1) * 16)) & 0xffffu);
      uint4 v = ((const uint4*)(x16 + (size_t)s * D))[q];
      float2 t;
      t = h2f2(v.x); a[0] += t.x; a[1] += t.y;
      t = h2f2(v.y); a[2] += t.x; a[3] += t.y;
      t = h2f2(v.z); a[4] += t.x; a[5] += t.y;
      t = h2f2(v.w); a[6] += t.x; a[7] += t.y;
    }
    int rem = deg - e;
    if (rem > 0) {
      unsigned u = __shfl(w, c * 16 + ((e + g) >> 1));
      if (g < rem) {
        int s = base + (int)((u >> (((e + g) & 1) * 16)) & 0xffffu);
        uint4 v = ((const uint4*)(x16 + (size_t)s * D))[q];
        float2 t;
        t = h2f2(v.x); a[0] += t.x; a[1] += t.y;
        t = h2f2(v.y); a[2] += t.x; a[3] += t.y;
        t = h2f2(v.z); a[4] += t.x; a[5] += t.y;
        t = h2f2(v.w); a[6] += t.x; a[7] += t.y;
      }
    }
  }
#pragma unroll
  for (int o = 8; o <= 32; o <<= 1) {
#pragma unroll
    for (int i = 0; i < 8; ++i) a[i] += __shfl_xor(a[i], o);
  }
  if (lane < 8) {
    __half2 h0 = __floats2half2_rn(a[0], a[1]);
    __half2 h1 = __floats2half2_rn(a[2], a[3]);
    __half2 h2 = __floats2half2_rn(a[4], a[5]);
    __half2 h3 = __floats2half2_rn(a[6], a[7]);
    uint4 out;
    out.x = *reinterpret_cast<unsigned*>(&h0);
    out.y = *reinterpret_cast<unsigned*>(&h1);
    out.z = *reinterpret_cast<unsigned*>(&h2);
    out.w = *reinterpret_cast<unsigned*>(&h3);
    ((uint4*)(agg16 + (size_t)wid * D))[q] = out;
  }
}

// ---------------------------------------------------------------------------
// FUSED layer on MFMA (v_mfma_f32_16x16x16f16). Verified layouts (R21).
__global__ __launch_bounds__(256) void k_layer(
    const __half* __restrict__ aggIn, const __half* __restrict__ xIn,
    const float* __restrict__ convw, const float* __restrict__ linw,
    const float* __restrict__ linb, const float* __restrict__ gw,
    const float* __restrict__ gb,
    __half* __restrict__ out16, float* __restrict__ outf, int do_leaky) {
  __shared__ __half sA[2][TR * ROWH];
  __shared__ __half sX[2][TR * ROWH];
  __shared__ __half sH[TR * ROWH];
  __shared__ __half sXH[TR * ROWH];
  int tid  = threadIdx.x;
  int lane = tid & 63;
  int wv   = tid >> 6;
  int r    = lane & 15;
  int g    = lane >> 4;
  int nt   = wv;

  v4h Bc[4], Bl[4], Bg1[4], Bg2[4];
#pragma unroll
  for (int ks = 0; ks < 4; ++ks) {
    v4h b;
#pragma unroll
    for (int j = 0; j < 4; ++j)
      b[j] = (_Float16)convw[(16 * ks + 4 * g + j) * D + 16 * nt + r];
    Bc[ks] = b;
    const float4 tl = *(const float4*)(linw + (size_t)(16 * nt + r) * D + 16 * ks + 4 * g);
    v4h bb; bb[0] = (_Float16)tl.x; bb[1] = (_Float16)tl.y;
    bb[2] = (_Float16)tl.z; bb[3] = (_Float16)tl.w;
    Bl[ks] = bb;
    const float4 t1 = *(const float4*)(gw + (size_t)(16 * nt + r) * 2 * D + 16 * ks + 4 * g);
    v4h b1; b1[0] = (_Float16)t1.x; b1[1] = (_Float16)t1.y;
    b1[2] = (_Float16)t1.z; b1[3] = (_Float16)t1.w;
    Bg1[ks] = b1;
    const float4 t2 = *(const float4*)(gw + (size_t)(16 * nt + r) * 2 * D + D + 16 * ks + 4 * g);
    v4h b2; b2[0] = (_Float16)t2.x; b2[1] = (_Float16)t2.y;
    b2[2] = (_Float16)t2.z; b2[3] = (_Float16)t2.w;
    Bg2[ks] = b2;
  }
  float bl = linb[16 * nt + r];
  float bg = gb[16 * nt + r];

  const int ntile = NTOT / TR;
  int srow = tid >> 3;
  int scol = (tid & 7) * 8;
  uint4 pA, pX;
  int t = blockIdx.x;
  pA = ((const uint4*)(aggIn + (size_t)t * TR * D))[tid];
  pX = ((const uint4*)(xIn + (size_t)t * TR * D))[tid];
  *(uint4*)&sA[0][srow * ROWH + scol] = pA;
  *(uint4*)&sX[0][srow * ROWH + scol] = pX;
  __syncthreads();
  int buf = 0;
  for (; t < ntile; t += gridDim.x) {
    int tn = t + gridDim.x;
    if (tn < ntile) {
      pA = ((const uint4*)(aggIn + (size_t)tn * TR * D))[tid];
      pX = ((const uint4*)(xIn + (size_t)tn * TR * D))[tid];
    }
#pragma unroll
    for (int mt = 0; mt < 2; ++mt) {
      v4f ah = {0.f, 0.f, 0.f, 0.f};
      v4f ax = {bl, bl, bl, bl};
#pragma unroll
      for (int ks = 0; ks < 4; ++ks) {
        v4h aAgg = __builtin_bit_cast(v4h,
            *(const unsigned long long*)&sA[buf][(16 * mt + r) * ROWH + 16 * ks + 4 * g]);
        v4h aXf = __builtin_bit_cast(v4h,
            *(const unsigned long long*)&sX[buf][(16 * mt + r) * ROWH + 16 * ks + 4 * g]);
        ah = __builtin_amdgcn_mfma_f32_16x16x16f16(aAgg, Bc[ks], ah, 0, 0, 0);
        ax = __builtin_amdgcn_mfma_f32_16x16x16f16(aXf, Bl[ks], ax, 0, 0, 0);
      }
#pragma unroll
      for (int j = 0; j < 4; ++j) {
        sH[(16 * mt + 4 * g + j) * ROWH + 16 * nt + r]  = __float2half(leaky(ah[j]));
        sXH[(16 * mt + 4 * g + j) * ROWH + 16 * nt + r] = __float2half(leaky(ax[j]));
      }
    }
    __syncthreads();
    if (tn < ntile) {
      *(uint4*)&sA[buf ^ 1][srow * ROWH + scol] = pA;
      *(uint4*)&sX[buf ^ 1][srow * ROWH + scol] = pX;
    }
#pragma unroll
    for (int mt = 0; mt < 2; ++mt) {
      v4f ag = {bg, bg, bg, bg};
#pragma unroll
      for (int ks = 0; ks < 4; ++ks) {
        v4h fh = __builtin_bit_cast(v4h,
            *(const unsigned long long*)&sH[(16 * mt + r) * ROWH + 16 * ks + 4 * g]);
        ag = __builtin_amdgcn_mfma_f32_16x16x16f16(fh, Bg1[ks], ag, 0, 0, 0);
      }
#pragma unroll
      for (int ks = 0; ks < 4; ++ks) {
        v4h fx = __builtin_bit_cast(v4h,
            *(const unsigned long long*)&sXH[(16 * mt + r) * ROWH + 16 * ks + 4 * g]);
        ag = __builtin_amdgcn_mfma_f32_16x16x16f16(fx, Bg2[ks], ag, 0, 0, 0);
      }
#pragma unroll
      for (int j = 0; j < 4; ++j) {
        float o = ag[j];
        if (do_leaky) o = leaky(o);
        size_t gi = ((size_t)t * TR + 16 * mt + 4 * g + j) * D + 16 * nt + r;
        if (out16) out16[gi] = __float2half(o);
        else       outf[gi] = o;
      }
    }
    __syncthreads();
    buf ^= 1;
  }
}

// ---------------------------------------------------------------------------
extern "C" void kernel_launch(void* const* d_in, const int* in_sizes, int n_in,
                              void* d_out, int out_size, void* d_ws, size_t ws_size,
                              hipStream_t stream) {
  const float* features = (const float*)d_in[0];
  const int*   ei       = (const int*)d_in[1];
  const float* pref     = (const float*)d_in[2];
  const float* mlp_w    = (const float*)d_in[3];
  const float* mlp_b    = (const float*)d_in[4];
  const float* conv_w[5]; const float* lin_w[5]; const float* lin_b[5];
  const float* g_w[5];    const float* g_b[5];
  if (n_in >= 30) {
    for (int i = 0; i < 5; ++i) {
      conv_w[i] = (const float*)d_in[5 + i];
      lin_w[i]  = (const float*)d_in[10 + i];
      lin_b[i]  = (const float*)d_in[15 + i];
      g_w[i]    = (const float*)d_in[20 + i];
      g_b[i]    = (const float*)d_in[25 + i];
    }
  } else {
    const float* cw = (const float*)d_in[5];
    const float* lw = (const float*)d_in[6];
    const float* lb = (const float*)d_in[7];
    const float* gw = (const float*)d_in[8];
    const float* gb = (const float*)d_in[9];
    for (int i = 0; i < 5; ++i) {
      conv_w[i] = cw + (size_t)i * D * D;
      lin_w[i]  = lw + (size_t)i * D * D;
      lin_b[i]  = lb + (size_t)i * D;
      g_w[i]    = gw + (size_t)i * D * 2 * D;
      g_b[i]    = gb + (size_t)i * D;
    }
  }
  const int* e_src = ei;
  const int* e_dst = ei + NE;

  char* p = (char*)d_ws;
  __half* x16a  = (__half*)p; p += (size_t)NTOT * D * 2;     // 12.8 MB
  __half* x16b  = (__half*)p; p += (size_t)NTOT * D * 2;     // 12.8 MB
  __half* agg16 = (__half*)p; p += (size_t)NTOT * D * 2;     // 12.8 MB
  __half* h16   = (__half*)p; p += (size_t)NTOT * D * 2;     // 12.8 MB (part alias)
  __half* xh16  = (__half*)p; p += (size_t)NTOT * D * 2;     // 12.8 MB (spare)
  unsigned short* csr = (unsigned short*)p; p += (size_t)NTOT * CAP * 2;  // 25.6 MB
  int*   cursor = (int*)p;   p += (size_t)NTOT * NCHUNK * 4; // 1.6 MB
  int*   wcur   = (int*)p;   p += (NW + 64) * 4;
  unsigned* part = (unsigned*)h16;
  (void)xh16;

  float* mu     = (float*)d_out;
  float* logvar = (float*)d_out + (size_t)NTOT * D;

  const int WPB = 4;
  int grid_rows  = (NTOT + WPB - 1) / WPB;        // 25000
  int grid_dense = 1563;                          // 2 tiles per block (3125 tiles)
  int ntile_item = (NITEM + TR - 1) / TR;         // 1563

  k_init_user<<<(NUSER + 3) / 4, 256, 0, stream>>>(pref, x16a, wcur);
  k_init_item<<<ntile_item, 512, 0, stream>>>(features, mlp_w, mlp_b, x16a);

  // Bucket CSR via single-pass 1024-way-parallel partition + LDS scatter
  k_part<<<PBLK, 256, 0, stream>>>(e_src, e_dst, wcur, part);
  k_scatter_lds<<<NW, 256, 0, stream>>>(part, wcur, cursor, csr);

  __half* xa = x16a;
  __half* xb = x16b;
  for (int i = 0; i < 3; ++i) {
    k_agg<<<grid_rows, 256, 0, stream>>>(xa, cursor, csr, agg16);
    k_layer<<<grid_dense, 256, 0, stream>>>(agg16, xa, conv_w[i], lin_w[i], lin_b[i],
                                            g_w[i], g_b[i], xb, nullptr, 1);
    __half* t = xa; xa = xb; xb = t;
  }

  // Heads share one aggregation of the final x.
  k_agg<<<grid_rows, 256, 0, stream>>>(xa, cursor, csr, agg16);
  k_layer<<<grid_dense, 256, 0, stream>>>(agg16, xa, conv_w[3], lin_w[3], lin_b[3],
                                          g_w[3], g_b[3], nullptr, mu, 0);
  k_layer<<<grid_dense, 256, 0, stream>>>(agg16, xa, conv_w[4], lin_w[4], lin_b[4],
                                          g_w[4], g_b[4], nullptr, logvar, 0);
}

// Round 24
// 375.181 us; speedup vs baseline: 1.0734x; 1.0734x over previous
//
#include <hip/hip_runtime.h>
#include <hip/hip_fp16.h>

#define DEVINL __device__ __forceinline__

typedef _Float16 v4h __attribute__((ext_vector_type(4)));
typedef float    v4f __attribute__((ext_vector_type(4)));

constexpr int NUSER = 50000;
constexpr int NITEM = 50000;
constexpr int NTOT  = 100000;   // NUM_USER + NUM_ITEM
constexpr int DF    = 128;
constexpr int D     = 64;
constexpr int NE    = 2000000;
constexpr int TR    = 32;       // tile rows (100000/32 = 3125 tiles)
constexpr int ROWH  = 72;       // padded LDS row stride (halves)
constexpr int NCHUNK = 4;                             // src chunks (3.2MB < 4MB L2)
constexpr int CSPAN  = NTOT / NCHUNK;                 // 25000
constexpr int CCAP   = 32;      // per-chunk cap: 32 u16 = one 64B line
constexpr int CAP    = NCHUNK * CCAP;                 // 128 u16 slots/node
constexpr int NW     = 512;     // node windows
constexpr int NPW    = 196;     // nodes per window
constexpr int WCAP   = 4608;    // per-window stream cap
constexpr int PBLK   = 512;                           // partition blocks (R22-proven)
constexpr int EPB    = (NE + PBLK - 1) / PBLK;        // 3907 edges/block
constexpr int EPT    = (EPB + 255) / 256;             // 16 entries/thread

DEVINL float leaky(float v) { return v > 0.f ? v : 0.01f * v; }

DEVINL float2 h2f2(unsigned u) {
  __half2 h = *reinterpret_cast<__half2*>(&u);
  return __half22float2(h);
}

// ---------------------------------------------------------------------------
// User half of init: x16[r] = normalize(pref[r]). One wave per row.
// Block 0 also zeroes wcur (saves a separate k_zero dispatch).
__global__ __launch_bounds__(256) void k_init_user(
    const float* __restrict__ pref, __half* __restrict__ x16,
    int* __restrict__ wcur) {
  if (blockIdx.x == 0) {
    for (int i = threadIdx.x; i < NW + 64; i += 256) wcur[i] = 0;
  }
  int wid  = (blockIdx.x * blockDim.x + threadIdx.x) >> 6;
  int lane = threadIdx.x & 63;
  if (wid >= NUSER) return;
  float v = pref[(size_t)wid * D + lane];
  float ss = v * v;
#pragma unroll
  for (int o = 32; o; o >>= 1) ss += __shfl_xor(ss, o);
  float inv = 1.0f / fmaxf(sqrtf(ss), 1e-12f);
  x16[(size_t)wid * D + lane] = __float2half(v * inv);
}

// Item half: x16[NUSER+r] = normalize(feat[r] @ mlp_w.T + mlp_b).
__global__ __launch_bounds__(512) void k_init_item(
    const float* __restrict__ feat, const float* __restrict__ mlp_w,
    const float* __restrict__ mlp_b, __half* __restrict__ x16) {
  __shared__ float sF[TR * DF];        // 16 KB feature tile
  __shared__ float sP[2][TR][D];       // 16 KB partial sums (per k-half)
  int tid  = threadIdx.x;
  int lane = tid & 63;
  int wv   = tid >> 6;     // 0..7
  int kh   = wv & 1;       // k-half
  int rg   = wv >> 1;      // row group 0..3
  float wh[D];
  const float4* wp = (const float4*)(mlp_w + (size_t)lane * DF + kh * D);
#pragma unroll
  for (int k = 0; k < D / 4; ++k) {
    float4 t = wp[k];
    wh[4 * k] = t.x; wh[4 * k + 1] = t.y; wh[4 * k + 2] = t.z; wh[4 * k + 3] = t.w;
  }
  float bias = mlp_b[lane];
  int t = blockIdx.x;
  {
    const float4* base = (const float4*)(feat + (size_t)t * TR * DF);
    float4* dstl = (float4*)sF;
#pragma unroll
    for (int s = 0; s < 2; ++s) {
      int slot = tid + s * 512;
      int gr = t * TR + (slot >> 5);
      float4 v = make_float4(0.f, 0.f, 0.f, 0.f);
      if (gr < NITEM) v = base[slot];
      dstl[slot] = v;
    }
  }
  __syncthreads();
#pragma unroll
  for (int rr = 0; rr < 8; ++rr) {
    int r = rg * 8 + rr;
    const float4* fr = (const float4*)&sF[r * DF + kh * D];
    float acc = 0.f;
#pragma unroll
    for (int k = 0; k < D / 4; ++k) {
      float4 a = fr[k];   // uniform LDS read -> broadcast
      acc += a.x * wh[4 * k] + a.y * wh[4 * k + 1] + a.z * wh[4 * k + 2] + a.w * wh[4 * k + 3];
    }
    sP[kh][r][lane] = acc;
  }
  __syncthreads();
#pragma unroll
  for (int rr = 0; rr < 4; ++rr) {
    int r = wv * 4 + rr;
    int gr = t * TR + r;
    float v = sP[0][r][lane] + sP[1][r][lane] + bias;
    float ss = v * v;
#pragma unroll
    for (int o = 32; o; o >>= 1) ss += __shfl_xor(ss, o);
    float inv = 1.0f / fmaxf(sqrtf(ss), 1e-12f);
    if (gr < NITEM) x16[(size_t)(NUSER + gr) * D + lane] = __float2half(v * inv);
  }
}

// ---------------------------------------------------------------------------
// Phase 1: SINGLE-PASS LDS-buffered 512-way partition (R22 configuration).
// Each thread caches its <=EPT packed entries + window ids in REGISTERS
// during the histogram pass; the scatter pass runs from registers.
__global__ __launch_bounds__(256) void k_part(
    const int* __restrict__ src, const int* __restrict__ dst,
    int* __restrict__ wcur, unsigned* __restrict__ part) {
  __shared__ int hcnt[NW];      // 2 KB
  __shared__ int sc[NW];        // 2 KB (inclusive scan)
  __shared__ int gbase[NW];     // 2 KB
  __shared__ int hcur[NW];      // 2 KB
  __shared__ unsigned buf[EPB]; // 15.6 KB
  int tid = threadIdx.x;
  int e0 = blockIdx.x * EPB, e1 = min(NE, e0 + EPB);
  for (int i = tid; i < NW; i += 256) { hcnt[i] = 0; hcur[i] = 0; }
  __syncthreads();
  unsigned ent[EPT];
  int wid[EPT];
#pragma unroll
  for (int i = 0; i < EPT; ++i) {
    int e = e0 + tid + i * 256;
    int w = -1; unsigned v = 0;
    if (e < e1) {
      int d = dst[e];
      int s = src[e];
      w = d / NPW;
      v = ((unsigned)(d - w * NPW) << 17) | (unsigned)s;
      atomicAdd(&hcnt[w], 1);
    }
    ent[i] = v; wid[i] = w;
  }
  __syncthreads();
  // inclusive Hillis-Steele over NW=512 with 256 threads (2 elems/thread)
  {
    int i0 = tid, i1 = tid + 256;
    sc[i0] = hcnt[i0]; sc[i1] = hcnt[i1];
    __syncthreads();
    for (int o = 1; o < NW; o <<= 1) {
      int v0 = (i0 >= o) ? sc[i0 - o] : 0;
      int v1 = (i1 >= o) ? sc[i1 - o] : 0;
      __syncthreads();
      sc[i0] += v0; sc[i1] += v1;
      __syncthreads();
    }
  }
  // global reservation: 512 concurrent atomics on distinct addresses
  for (int i = tid; i < NW; i += 256)
    gbase[i] = atomicAdd(&wcur[i], hcnt[i]);
  __syncthreads();
  // scatter from registers into LDS-bucketed runs
#pragma unroll
  for (int i = 0; i < EPT; ++i) {
    int w = wid[i];
    if (w >= 0) {
      int idx = atomicAdd(&hcur[w], 1);
      buf[sc[w] - hcnt[w] + idx] = ent[i];
    }
  }
  __syncthreads();
  // write-out: wave v handles bins v, v+4, ... (each bin ~8 entries)
  int wvv = tid >> 6, lane = tid & 63;
  for (int b = wvv; b < NW; b += 4) {
    int len = hcnt[b];
    int lb = sc[b] - len;
    int gb = gbase[b];
    unsigned* out = part + (size_t)b * WCAP;
    for (int i = lane; i < len; i += 64)
      if (gb + i < WCAP) out[gb + i] = buf[lb + i];
  }
}

// ---------------------------------------------------------------------------
// Phase 2: LDS-bucketed scatter (reads only its own stream, coalesced out).
__global__ __launch_bounds__(256) void k_scatter_lds(
    const unsigned* __restrict__ part, const int* __restrict__ wcur,
    int* __restrict__ cursor, unsigned short* __restrict__ csr) {
  __shared__ unsigned short lbuck[NPW * CAP];
  __shared__ int lcur[NPW * NCHUNK];
  int tid = threadIdx.x;
  int w   = blockIdx.x;
  int nlo = w * NPW;
  int nn  = min(NPW, NTOT - nlo);
  if (nn <= 0) return;
  for (int i = tid; i < NPW * NCHUNK; i += 256) lcur[i] = 0;
  __syncthreads();
  int cnt = min(wcur[w], WCAP);
  const unsigned* basep = part + (size_t)w * WCAP;
  for (int e = tid; e < cnt; e += 256) {
    unsigned v = basep[e];
    int dl = (int)(v >> 17);
    int s  = (int)(v & 0x1ffffu);
    int c  = s / CSPAN;
    int p  = atomicAdd(&lcur[dl * NCHUNK + c], 1);
    if (p < CCAP) lbuck[dl * CAP + c * CCAP + p] = (unsigned short)(s - c * CSPAN);
  }
  __syncthreads();
  unsigned* gcsr = (unsigned*)(csr + (size_t)nlo * CAP);
  const unsigned* lsrc = (const unsigned*)lbuck;
  int words = nn * (CAP / 2);
  for (int i = tid; i < words; i += 256) gcsr[i] = lsrc[i];
  int* gcur = cursor + (size_t)nlo * NCHUNK;
  for (int i = tid; i < nn * NCHUNK; i += 256) gcur[i] = lcur[i];
}

// ---------------------------------------------------------------------------
// agg16[n] = fp16( sum over bucket of x16[src] ), f32 accum. CONVERGENT shfl.
__global__ __launch_bounds__(256) void k_agg(
    const __half* __restrict__ x16, const int* __restrict__ cnt,
    const unsigned short* __restrict__ csr, __half* __restrict__ agg16) {
  int wid  = (blockIdx.x * blockDim.x + threadIdx.x) >> 6;
  int lane = threadIdx.x & 63;
  if (wid >= NTOT) return;
  int g = lane >> 3;
  int q = lane & 7;
  int4 c4 = *(const int4*)(cnt + ((size_t)wid << 2));
  unsigned w = ((const unsigned*)(csr + (size_t)wid * CAP))[lane];
  float a[8] = {0.f, 0.f, 0.f, 0.f, 0.f, 0.f, 0.f, 0.f};
#pragma unroll
  for (int c = 0; c < NCHUNK; ++c) {
    int deg = min(c == 0 ? c4.x : c == 1 ? c4.y : c == 2 ? c4.z : c4.w, CCAP);
    int base = c * CSPAN;
    int e = 0;
    for (; e + 8 <= deg; e += 8) {
      unsigned u = __shfl(w, c * 16 + ((e + g) >> 1));
      int s = base + (int)((u >> (((e + g) & 1) * 16)) & 0xffffu);
      uint4 v = ((const uint4*)(x16 + (size_t)s * D))[q];
      float2 t;
      t = h2f2(v.x); a[0] += t.x; a[1] += t.y;
      t = h2f2(v.y); a[2] += t.x; a[3] += t.y;
      t = h2f2(v.z); a[4] += t.x; a[5] += t.y;
      t = h2f2(v.w); a[6] += t.x; a[7] += t.y;
    }
    int rem = deg - e;
    if (rem > 0) {
      unsigned u = __shfl(w, c * 16 + ((e + g) >> 1));
      if (g < rem) {
        int s = base + (int)((u >> (((e + g) & 1) * 16)) & 0xffffu);
        uint4 v = ((const uint4*)(x16 + (size_t)s * D))[q];
        float2 t;
        t = h2f2(v.x); a[0] += t.x; a[1] += t.y;
        t = h2f2(v.y); a[2] += t.x; a[3] += t.y;
        t = h2f2(v.z); a[4] += t.x; a[5] += t.y;
        t = h2f2(v.w); a[6] += t.x; a[7] += t.y;
      }
    }
  }
#pragma unroll
  for (int o = 8; o <= 32; o <<= 1) {
#pragma unroll
    for (int i = 0; i < 8; ++i) a[i] += __shfl_xor(a[i], o);
  }
  if (lane < 8) {
    __half2 h0 = __floats2half2_rn(a[0], a[1]);
    __half2 h1 = __floats2half2_rn(a[2], a[3]);
    __half2 h2 = __floats2half2_rn(a[4], a[5]);
    __half2 h3 = __floats2half2_rn(a[6], a[7]);
    uint4 out;
    out.x = *reinterpret_cast<unsigned*>(&h0);
    out.y = *reinterpret_cast<unsigned*>(&h1);
    out.z = *reinterpret_cast<unsigned*>(&h2);
    out.w = *reinterpret_cast<unsigned*>(&h3);
    ((uint4*)(agg16 + (size_t)wid * D))[q] = out;
  }
}

// ---------------------------------------------------------------------------
// FUSED layer on MFMA (v_mfma_f32_16x16x16f16). Verified layouts (R21).
__global__ __launch_bounds__(256) void k_layer(
    const __half* __restrict__ aggIn, const __half* __restrict__ xIn,
    const float* __restrict__ convw, const float* __restrict__ linw,
    const float* __restrict__ linb, const float* __restrict__ gw,
    const float* __restrict__ gb,
    __half* __restrict__ out16, float* __restrict__ outf, int do_leaky) {
  __shared__ __half sA[2][TR * ROWH];
  __shared__ __half sX[2][TR * ROWH];
  __shared__ __half sH[TR * ROWH];
  __shared__ __half sXH[TR * ROWH];
  int tid  = threadIdx.x;
  int lane = tid & 63;
  int wv   = tid >> 6;
  int r    = lane & 15;
  int g    = lane >> 4;
  int nt   = wv;

  v4h Bc[4], Bl[4], Bg1[4], Bg2[4];
#pragma unroll
  for (int ks = 0; ks < 4; ++ks) {
    v4h b;
#pragma unroll
    for (int j = 0; j < 4; ++j)
      b[j] = (_Float16)convw[(16 * ks + 4 * g + j) * D + 16 * nt + r];
    Bc[ks] = b;
    const float4 tl = *(const float4*)(linw + (size_t)(16 * nt + r) * D + 16 * ks + 4 * g);
    v4h bb; bb[0] = (_Float16)tl.x; bb[1] = (_Float16)tl.y;
    bb[2] = (_Float16)tl.z; bb[3] = (_Float16)tl.w;
    Bl[ks] = bb;
    const float4 t1 = *(const float4*)(gw + (size_t)(16 * nt + r) * 2 * D + 16 * ks + 4 * g);
    v4h b1; b1[0] = (_Float16)t1.x; b1[1] = (_Float16)t1.y;
    b1[2] = (_Float16)t1.z; b1[3] = (_Float16)t1.w;
    Bg1[ks] = b1;
    const float4 t2 = *(const float4*)(gw + (size_t)(16 * nt + r) * 2 * D + D + 16 * ks + 4 * g);
    v4h b2; b2[0] = (_Float16)t2.x; b2[1] = (_Float16)t2.y;
    b2[2] = (_Float16)t2.z; b2[3] = (_Float16)t2.w;
    Bg2[ks] = b2;
  }
  float bl = linb[16 * nt + r];
  float bg = gb[16 * nt + r];

  const int ntile = NTOT / TR;
  int srow = tid >> 3;
  int scol = (tid & 7) * 8;
  uint4 pA, pX;
  int t = blockIdx.x;
  pA = ((const uint4*)(aggIn + (size_t)t * TR * D))[tid];
  pX = ((const uint4*)(xIn + (size_t)t * TR * D))[tid];
  *(uint4*)&sA[0][srow * ROWH + scol] = pA;
  *(uint4*)&sX[0][srow * ROWH + scol] = pX;
  __syncthreads();
  int buf = 0;
  for (; t < ntile; t += gridDim.x) {
    int tn = t + gridDim.x;
    if (tn < ntile) {
      pA = ((const uint4*)(aggIn + (size_t)tn * TR * D))[tid];
      pX = ((const uint4*)(xIn + (size_t)tn * TR * D))[tid];
    }
#pragma unroll
    for (int mt = 0; mt < 2; ++mt) {
      v4f ah = {0.f, 0.f, 0.f, 0.f};
      v4f ax = {bl, bl, bl, bl};
#pragma unroll
      for (int ks = 0; ks < 4; ++ks) {
        v4h aAgg = __builtin_bit_cast(v4h,
            *(const unsigned long long*)&sA[buf][(16 * mt + r) * ROWH + 16 * ks + 4 * g]);
        v4h aXf = __builtin_bit_cast(v4h,
            *(const unsigned long long*)&sX[buf][(16 * mt + r) * ROWH + 16 * ks + 4 * g]);
        ah = __builtin_amdgcn_mfma_f32_16x16x16f16(aAgg, Bc[ks], ah, 0, 0, 0);
        ax = __builtin_amdgcn_mfma_f32_16x16x16f16(aXf, Bl[ks], ax, 0, 0, 0);
      }
#pragma unroll
      for (int j = 0; j < 4; ++j) {
        sH[(16 * mt + 4 * g + j) * ROWH + 16 * nt + r]  = __float2half(leaky(ah[j]));
        sXH[(16 * mt + 4 * g + j) * ROWH + 16 * nt + r] = __float2half(leaky(ax[j]));
      }
    }
    __syncthreads();
    if (tn < ntile) {
      *(uint4*)&sA[buf ^ 1][srow * ROWH + scol] = pA;
      *(uint4*)&sX[buf ^ 1][srow * ROWH + scol] = pX;
    }
#pragma unroll
    for (int mt = 0; mt < 2; ++mt) {
      v4f ag = {bg, bg, bg, bg};
#pragma unroll
      for (int ks = 0; ks < 4; ++ks) {
        v4h fh = __builtin_bit_cast(v4h,
            *(const unsigned long long*)&sH[(16 * mt + r) * ROWH + 16 * ks + 4 * g]);
        ag = __builtin_amdgcn_mfma_f32_16x16x16f16(fh, Bg1[ks], ag, 0, 0, 0);
      }
#pragma unroll
      for (int ks = 0; ks < 4; ++ks) {
        v4h fx = __builtin_bit_cast(v4h,
            *(const unsigned long long*)&sXH[(16 * mt + r) * ROWH + 16 * ks + 4 * g]);
        ag = __builtin_amdgcn_mfma_f32_16x16x16f16(fx, Bg2[ks], ag, 0, 0, 0);
      }
#pragma unroll
      for (int j = 0; j < 4; ++j) {
        float o = ag[j];
        if (do_leaky) o = leaky(o);
        size_t gi = ((size_t)t * TR + 16 * mt + 4 * g + j) * D + 16 * nt + r;
        if (out16) out16[gi] = __float2half(o);
        else       outf[gi] = o;
      }
    }
    __syncthreads();
    buf ^= 1;
  }
}

// ---------------------------------------------------------------------------
extern "C" void kernel_launch(void* const* d_in, const int* in_sizes, int n_in,
                              void* d_out, int out_size, void* d_ws, size_t ws_size,
                              hipStream_t stream) {
  const float* features = (const float*)d_in[0];
  const int*   ei       = (const int*)d_in[1];
  const float* pref     = (const float*)d_in[2];
  const float* mlp_w    = (const float*)d_in[3];
  const float* mlp_b    = (const float*)d_in[4];
  const float* conv_w[5]; const float* lin_w[5]; const float* lin_b[5];
  const float* g_w[5];    const float* g_b[5];
  if (n_in >= 30) {
    for (int i = 0; i < 5; ++i) {
      conv_w[i] = (const float*)d_in[5 + i];
      lin_w[i]  = (const float*)d_in[10 + i];
      lin_b[i]  = (const float*)d_in[15 + i];
      g_w[i]    = (const float*)d_in[20 + i];
      g_b[i]    = (const float*)d_in[25 + i];
    }
  } else {
    const float* cw = (const float*)d_in[5];
    const float* lw = (const float*)d_in[6];
    const float* lb = (const float*)d_in[7];
    const float* gw = (const float*)d_in[8];
    const float* gb = (const float*)d_in[9];
    for (int i = 0; i < 5; ++i) {
      conv_w[i] = cw + (size_t)i * D * D;
      lin_w[i]  = lw + (size_t)i * D * D;
      lin_b[i]  = lb + (size_t)i * D;
      g_w[i]    = gw + (size_t)i * D * 2 * D;
      g_b[i]    = gb + (size_t)i * D;
    }
  }
  const int* e_src = ei;
  const int* e_dst = ei + NE;

  char* p = (char*)d_ws;
  __half* x16a  = (__half*)p; p += (size_t)NTOT * D * 2;     // 12.8 MB
  __half* x16b  = (__half*)p; p += (size_t)NTOT * D * 2;     // 12.8 MB
  __half* agg16 = (__half*)p; p += (size_t)NTOT * D * 2;     // 12.8 MB
  __half* h16   = (__half*)p; p += (size_t)NTOT * D * 2;     // 12.8 MB (part alias)
  __half* xh16  = (__half*)p; p += (size_t)NTOT * D * 2;     // 12.8 MB (spare)
  unsigned short* csr = (unsigned short*)p; p += (size_t)NTOT * CAP * 2;  // 25.6 MB
  int*   cursor = (int*)p;   p += (size_t)NTOT * NCHUNK * 4; // 1.6 MB
  int*   wcur   = (int*)p;   p += (NW + 64) * 4;
  unsigned* part = (unsigned*)h16;
  (void)xh16;

  float* mu     = (float*)d_out;
  float* logvar = (float*)d_out + (size_t)NTOT * D;

  const int WPB = 4;
  int grid_rows  = (NTOT + WPB - 1) / WPB;        // 25000
  int grid_dense = 1024;                          // tile grid-stride (3125 tiles)
  int ntile_item = (NITEM + TR - 1) / TR;         // 1563

  k_init_user<<<(NUSER + 3) / 4, 256, 0, stream>>>(pref, x16a, wcur);
  k_init_item<<<ntile_item, 512, 0, stream>>>(features, mlp_w, mlp_b, x16a);

  // Bucket CSR via single-pass 512-way partition + LDS-bucketed scatter
  k_part<<<PBLK, 256, 0, stream>>>(e_src, e_dst, wcur, part);
  k_scatter_lds<<<NW, 256, 0, stream>>>(part, wcur, cursor, csr);

  __half* xa = x16a;
  __half* xb = x16b;
  for (int i = 0; i < 3; ++i) {
    k_agg<<<grid_rows, 256, 0, stream>>>(xa, cursor, csr, agg16);
    k_layer<<<grid_dense, 256, 0, stream>>>(agg16, xa, conv_w[i], lin_w[i], lin_b[i],
                                            g_w[i], g_b[i], xb, nullptr, 1);
    __half* t = xa; xa = xb; xb = t;
  }

  // Heads share one aggregation of the final x.
  k_agg<<<grid_rows, 256, 0, stream>>>(xa, cursor, csr, agg16);
  k_layer<<<grid_dense, 256, 0, stream>>>(agg16, xa, conv_w[3], lin_w[3], lin_b[3],
                                          g_w[3], g_b[3], nullptr, mu, 0);
  k_layer<<<grid_dense, 256, 0, stream>>>(agg16, xa, conv_w[4], lin_w[4], lin_b[4],
                                          g_w[4], g_b[4], nullptr, logvar, 0);
}